// Round 1
// baseline (12.996 us; speedup 1.0000x reference)
//
#include <hip/hip_runtime.h>

// RNN_Tensorized collapses: layers 2/3 receive sigma0 == 0, so their bilinear
// terms vanish -> h3[l,:,a] = elu(b3[l,a]) (batch-independent, layer-1 scan is
// dead code). Output out[b,l] = sigmoid(z1[l]-z0[l]) with
//   z_o[l] = sum_h elu(b3[l,h]) * Ws[l,h,o] + bs[l,o]
// i.e. a per-column constant broadcast over B=8192 rows.

#define B_DIM 8192
#define L_DIM 64
#define H_DIM 64

__global__ __launch_bounds__(256) void rnn_collapse_kernel(
    const float* __restrict__ b3,   // [L, H]
    const float* __restrict__ Ws,   // [L, H, 2]
    const float* __restrict__ bs,   // [L, 2]
    float* __restrict__ out)        // [B, L] fp32
{
    __shared__ float vals[L_DIM];
    const int tid = threadIdx.x;

    if (tid < L_DIM) {
        const int l = tid;
        float s0 = 0.0f, s1 = 0.0f;
        #pragma unroll
        for (int h = 0; h < H_DIM; ++h) {
            float b = b3[l * H_DIM + h];
            float e = (b > 0.0f) ? b : (expf(b) - 1.0f);   // elu, alpha=1
            s0 += e * Ws[l * (H_DIM * 2) + h * 2 + 0];
            s1 += e * Ws[l * (H_DIM * 2) + h * 2 + 1];
        }
        const float z0 = s0 + bs[l * 2 + 0];
        const float z1 = s1 + bs[l * 2 + 1];
        // softmax(...)[1] = 1 / (1 + exp(z0 - z1))
        vals[l] = 1.0f / (1.0f + expf(z0 - z1));
    }
    __syncthreads();

    // out is [B, L] row-major; each float4 covers 4 consecutive l of one row.
    // Grid is sized so every thread writes exactly one float4.
    float4* __restrict__ out4 = (float4*)out;
    const int i = blockIdx.x * 256 + tid;
    const int l0 = (i * 4) & (L_DIM - 1);
    out4[i] = make_float4(vals[l0], vals[l0 + 1], vals[l0 + 2], vals[l0 + 3]);
}

extern "C" void kernel_launch(void* const* d_in, const int* in_sizes, int n_in,
                              void* d_out, int out_size, void* d_ws, size_t ws_size,
                              hipStream_t stream) {
    // setup_inputs order: 0 sigma_list, 1 W1, 2 b1, 3 W2, 4 b2, 5 W3, 6 b3, 7 Ws, 8 bs
    const float* b3 = (const float*)d_in[6];
    const float* Ws = (const float*)d_in[7];
    const float* bs = (const float*)d_in[8];
    float* out = (float*)d_out;

    const int n4 = out_size / 4;      // B*L/4 = 131072 float4 stores
    const int blocks = n4 / 256;      // 512 blocks x 256 threads, exact cover
    rnn_collapse_kernel<<<blocks, 256, 0, stream>>>(b3, Ws, bs, out);
}

// Round 2
// 9.624 us; speedup vs baseline: 1.3503x; 1.3503x over previous
//
#include <hip/hip_runtime.h>

// RNN_Tensorized collapses: layers 2/3 receive sigma0 == 0, so their bilinear
// terms vanish -> h3[l,:,a] = elu(b3[l,a]) (batch-independent; the layer-1
// scan is dead code). out[b,l] = sigmoid(z1[l]-z0[l]) with
//   z_o[l] = sum_h elu(b3[l,h]) * Ws[l,h,o] + bs[l,o]
// i.e. 64 scalars broadcast over B=8192 rows.
//
// R1: parallelize the per-l reduction over 4 lanes (all 256 threads active),
// float4 weight loads (192 scalar -> 12 vector loads/thread), shfl_xor reduce.

#define L_DIM 64
#define H_DIM 64

__device__ __forceinline__ float elu(float x) {
    return (x > 0.0f) ? x : (expf(x) - 1.0f);
}

__global__ __launch_bounds__(256) void rnn_collapse_kernel(
    const float* __restrict__ b3,   // [L, H]
    const float* __restrict__ Ws,   // [L, H, 2]
    const float* __restrict__ bs,   // [L, 2]
    float* __restrict__ out)        // [B, L] fp32
{
    __shared__ float vals[L_DIM];
    const int tid = threadIdx.x;
    const int l = tid >> 2;         // 0..63
    const int q = tid & 3;          // h-quarter: h in [16q, 16q+16)

    // Vector views of this thread's slice.
    const float4* __restrict__ b3v = (const float4*)(b3 + l * H_DIM + q * 16);       // 4 x float4
    const float4* __restrict__ Wsv = (const float4*)(Ws + l * (H_DIM * 2) + q * 32); // 8 x float4

    float s0 = 0.0f, s1 = 0.0f;
    #pragma unroll
    for (int i = 0; i < 4; ++i) {
        const float4 bv = b3v[i];
        const float4 w0 = Wsv[2 * i];      // [h4i+0].{o0,o1}, [h4i+1].{o0,o1}
        const float4 w1 = Wsv[2 * i + 1];  // [h4i+2].{o0,o1}, [h4i+3].{o0,o1}
        float e;
        e = elu(bv.x); s0 += e * w0.x; s1 += e * w0.y;
        e = elu(bv.y); s0 += e * w0.z; s1 += e * w0.w;
        e = elu(bv.z); s0 += e * w1.x; s1 += e * w1.y;
        e = elu(bv.w); s0 += e * w1.z; s1 += e * w1.w;
    }
    // Reduce across the 4 lanes sharing one l.
    s0 += __shfl_xor(s0, 1); s1 += __shfl_xor(s1, 1);
    s0 += __shfl_xor(s0, 2); s1 += __shfl_xor(s1, 2);

    if (q == 0) {
        const float z0 = s0 + bs[l * 2 + 0];
        const float z1 = s1 + bs[l * 2 + 1];
        vals[l] = 1.0f / (1.0f + expf(z0 - z1));   // softmax(...)[1]
    }
    __syncthreads();

    // out is [B, L] row-major; each float4 covers 4 consecutive l of one row.
    float4* __restrict__ out4 = (float4*)out;
    const int i = blockIdx.x * 256 + tid;
    const int l0 = (i * 4) & (L_DIM - 1);
    out4[i] = *(const float4*)&vals[l0];   // 16B-aligned LDS read
}

extern "C" void kernel_launch(void* const* d_in, const int* in_sizes, int n_in,
                              void* d_out, int out_size, void* d_ws, size_t ws_size,
                              hipStream_t stream) {
    // setup_inputs order: 0 sigma_list, 1 W1, 2 b1, 3 W2, 4 b2, 5 W3, 6 b3, 7 Ws, 8 bs
    const float* b3 = (const float*)d_in[6];
    const float* Ws = (const float*)d_in[7];
    const float* bs = (const float*)d_in[8];
    float* out = (float*)d_out;

    const int n4 = out_size / 4;      // B*L/4 = 131072 float4 stores
    const int blocks = n4 / 256;      // 512 blocks x 256 threads, exact cover
    rnn_collapse_kernel<<<blocks, 256, 0, stream>>>(b3, Ws, bs, out);
}